// Round 3
// baseline (2367.290 us; speedup 1.0000x reference)
//
#include <hip/hip_runtime.h>

#define CH 64
#define ROWS_PB 32
#define NWAVE 8
#define BLOCK (NWAVE * 64)

// Kernel A: row_ptr[r] = first edge index e with edge_row[e] >= r  (r in [0, N])
__global__ __launch_bounds__(256) void build_row_ptr(
    const int* __restrict__ erow, int* __restrict__ rp, int N, int E)
{
    int r = blockIdx.x * 256 + threadIdx.x;
    if (r > N) return;
    int lo = 0, len = E;
    while (len > 0) {
        int half = len >> 1;
        int probe = lo + half;
        int v = erow[probe];
        if (v < r) { lo = probe + 1; len -= half + 1; }
        else { len = half; }
    }
    rp[r] = lo;
}

// Kernel B: block owns 32 rows; 8 waves process 64-edge batches edge-parallel.
// Metadata: one coalesced vector load per 64 edges, broadcast via readlane.
// Accumulation: ds_add_f32 into acc[32][4][64] (lane=channel, conflict-free).
// Epilogue: fused matvec with packed W in LDS.
__global__ __launch_bounds__(BLOCK, 2) void sdconv_fused(
    const float* __restrict__ Xr, const float* __restrict__ Xi,
    const float* __restrict__ Lr, const float* __restrict__ Li,
    const float* __restrict__ W, const float* __restrict__ bias,
    const int* __restrict__ erow, const int* __restrict__ ecol,
    const int* __restrict__ rp,
    float* __restrict__ outR, float* __restrict__ outI,
    int N, int E)
{
    __shared__ float4 w_pk[(CH / 2) * CH];            // 32 KB: {w0[c],w0[c+1],w1[c],w1[c+1]} at [c/2][lane]
    __shared__ float  acc[ROWS_PB][4][CH];            // 32 KB: A0,A1,B0,B1 per row

    const int t    = threadIdx.x;
    const int lane = t & 63;
    const int wave = t >> 6;
    const int r0   = blockIdx.x * ROWS_PB;

    // stage packed W
    for (int i = t; i < (CH / 2) * CH; i += BLOCK) {
        int c2 = i >> 6, j = i & 63;
        int c = c2 * 2;
        w_pk[i] = make_float4(W[c * CH + j], W[(c + 1) * CH + j],
                              W[CH * CH + c * CH + j], W[CH * CH + (c + 1) * CH + j]);
    }
    // zero accumulators
    float* accf = &acc[0][0][0];
    for (int i = t; i < ROWS_PB * 4 * CH; i += BLOCK) accf[i] = 0.f;
    __syncthreads();

    const int rend = (r0 + ROWS_PB < N) ? (r0 + ROWS_PB) : N;
    const int s_bs = __builtin_amdgcn_readfirstlane(rp[r0]);
    const int s_be = __builtin_amdgcn_readfirstlane(rp[rend]);
    const int cnt  = s_be - s_bs;

    const float* __restrict__ Lr1 = Lr + E;
    const float* __restrict__ Li1 = Li + E;

#define ISSUE(XR, XI, SB) do {                                                  \
    _Pragma("unroll")                                                           \
    for (int j_ = 0; j_ < 8; ++j_) {                                            \
        int c_ = __builtin_amdgcn_readlane(vcol, (SB) * 8 + j_);                \
        XR[j_] = Xr[c_ * CH + lane];                                            \
        XI[j_] = Xi[c_ * CH + lane];                                            \
    }                                                                           \
} while (0)

#define PROCESS(XR, XI, SB) do {                                                \
    _Pragma("unroll")                                                           \
    for (int j_ = 0; j_ < 8; ++j_) {                                            \
        int idx_ = (SB) * 8 + j_;                                               \
        float l0r_ = __uint_as_float(__builtin_amdgcn_readlane(__float_as_uint(vl0r), idx_)); \
        float l0i_ = __uint_as_float(__builtin_amdgcn_readlane(__float_as_uint(vl0i), idx_)); \
        float l1r_ = __uint_as_float(__builtin_amdgcn_readlane(__float_as_uint(vl1r), idx_)); \
        float l1i_ = __uint_as_float(__builtin_amdgcn_readlane(__float_as_uint(vl1i), idx_)); \
        int   lrow_ = __builtin_amdgcn_readlane(vrow, idx_);                    \
        float pa0_ = l0r_ * XR[j_] - l0i_ * XI[j_];                             \
        float pb0_ = l0i_ * XR[j_] + l0r_ * XI[j_];                             \
        float pa1_ = l1r_ * XR[j_] - l1i_ * XI[j_];                             \
        float pb1_ = l1i_ * XR[j_] + l1r_ * XI[j_];                             \
        float* p_ = &acc[lrow_][0][lane];                                       \
        atomicAdd(p_,           pa0_);                                          \
        atomicAdd(p_ + CH,      pa1_);                                          \
        atomicAdd(p_ + 2 * CH,  pb0_);                                          \
        atomicAdd(p_ + 3 * CH,  pb1_);                                          \
    }                                                                           \
} while (0)

    for (int b = wave * 64; b < cnt; b += NWAVE * 64) {
        int  eid  = s_bs + b + lane;
        bool ok   = (b + lane) < cnt;
        int  eidc = ok ? eid : (s_be - 1);
        int   vcol = ecol[eidc];
        int   vrow = (ok ? erow[eidc] : r0) - r0;
        float vl0r = ok ? Lr[eidc]  : 0.f;
        float vl0i = ok ? Li[eidc]  : 0.f;
        float vl1r = ok ? Lr1[eidc] : 0.f;
        float vl1i = ok ? Li1[eidc] : 0.f;

        float xrA[8], xiA[8], xrB[8], xiB[8];

        ISSUE(xrA, xiA, 0);
        ISSUE(xrB, xiB, 1);
        PROCESS(xrA, xiA, 0);
        ISSUE(xrA, xiA, 2);
        PROCESS(xrB, xiB, 1);
        ISSUE(xrB, xiB, 3);
        PROCESS(xrA, xiA, 2);
        ISSUE(xrA, xiA, 4);
        PROCESS(xrB, xiB, 3);
        ISSUE(xrB, xiB, 5);
        PROCESS(xrA, xiA, 4);
        ISSUE(xrA, xiA, 6);
        PROCESS(xrB, xiB, 5);
        ISSUE(xrB, xiB, 7);
        PROCESS(xrA, xiA, 6);
        PROCESS(xrB, xiB, 7);
    }
#undef ISSUE
#undef PROCESS

    __syncthreads();

    // Epilogue: out[row][j] = bias[j] + sum_c A0[c] w0[c][j] + A1[c] w1[c][j] (j=lane)
    const float bv = bias[lane];
    for (int r = wave; r < ROWS_PB; r += NWAVE) {
        int row = r0 + r;
        if (row >= N) break;
        const float* A = &acc[r][0][0];
        float2 aR = make_float2(0.f, 0.f), aI = make_float2(0.f, 0.f);
        #pragma unroll
        for (int c4 = 0; c4 < CH / 4; ++c4) {
            float4 A0 = *(const float4*)(A + 0 * CH + c4 * 4);   // broadcast b128
            float4 A1 = *(const float4*)(A + 1 * CH + c4 * 4);
            float4 B0 = *(const float4*)(A + 2 * CH + c4 * 4);
            float4 B1 = *(const float4*)(A + 3 * CH + c4 * 4);
            float4 wa = w_pk[(c4 * 2 + 0) * CH + lane];          // c = 4c4, 4c4+1
            float4 wb = w_pk[(c4 * 2 + 1) * CH + lane];          // c = 4c4+2, 4c4+3
            aR.x += A0.x * wa.x; aR.y += A0.y * wa.y;
            aR.x += A1.x * wa.z; aR.y += A1.y * wa.w;
            aI.x += B0.x * wa.x; aI.y += B0.y * wa.y;
            aI.x += B1.x * wa.z; aI.y += B1.y * wa.w;
            aR.x += A0.z * wb.x; aR.y += A0.w * wb.y;
            aR.x += A1.z * wb.z; aR.y += A1.w * wb.w;
            aI.x += B0.z * wb.x; aI.y += B0.w * wb.y;
            aI.x += B1.z * wb.z; aI.y += B1.w * wb.w;
        }
        outR[row * CH + lane] = aR.x + aR.y + bv;
        outI[row * CH + lane] = aI.x + aI.y + bv;
    }
}

extern "C" void kernel_launch(void* const* d_in, const int* in_sizes, int n_in,
                              void* d_out, int out_size, void* d_ws, size_t ws_size,
                              hipStream_t stream)
{
    const float* Xr   = (const float*)d_in[0];
    const float* Xi   = (const float*)d_in[1];
    const float* Lr   = (const float*)d_in[2];
    const float* Li   = (const float*)d_in[3];
    const float* W    = (const float*)d_in[4];
    const float* bias = (const float*)d_in[5];
    const int*   erow = (const int*)d_in[6];
    const int*   ecol = (const int*)d_in[7];

    const int N = in_sizes[0] / CH;
    const int E = in_sizes[6];

    int* rp = (int*)d_ws;                 // (N+1) ints of scratch
    float* outR = (float*)d_out;
    float* outI = outR + (size_t)N * CH;

    int nb_rp = (N + 1 + 255) / 256;
    hipLaunchKernelGGL(build_row_ptr, dim3(nb_rp), dim3(256), 0, stream,
                       erow, rp, N, E);

    int nb = (N + ROWS_PB - 1) / ROWS_PB;
    hipLaunchKernelGGL(sdconv_fused, dim3(nb), dim3(BLOCK), 0, stream,
                       Xr, Xi, Lr, Li, W, bias, erow, ecol, rp, outR, outI, N, E);
}

// Round 4
// 168.759 us; speedup vs baseline: 14.0276x; 14.0276x over previous
//
#include <hip/hip_runtime.h>

#define CH 64
#define ROWS_PER_BLOCK 8
#define BLOCK (ROWS_PER_BLOCK * 64)

__device__ __forceinline__ float rl_f(float v, int l) {
    return __uint_as_float(__builtin_amdgcn_readlane(__float_as_uint(v), l));
}

// Kernel A: row_ptr[r] = first edge index e with edge_row[e] >= r  (r in [0, N])
__global__ __launch_bounds__(256) void build_row_ptr(
    const int* __restrict__ erow, int* __restrict__ rp, int N, int E)
{
    int r = blockIdx.x * 256 + threadIdx.x;
    if (r > N) return;
    int lo = 0, len = E;
    while (len > 0) {
        int half = len >> 1;
        int probe = lo + half;
        int v = erow[probe];
        if (v < r) { lo = probe + 1; len -= half + 1; }
        else { len = half; }
    }
    rp[r] = lo;
}

// Issue 8 gathers (16 loads) for sub-batch SB into buffer BUF; pin the cluster.
#define ISSUE(BUF, SB)                                                      \
    do {                                                                    \
        _Pragma("unroll")                                                   \
        for (int j_ = 0; j_ < 8; ++j_) {                                    \
            int c_ = __builtin_amdgcn_readlane(vcol, (SB) * 8 + j_);        \
            xr##BUF[j_] = Xr[(size_t)c_ * CH + lane];                       \
            xi##BUF[j_] = Xi[(size_t)c_ * CH + lane];                       \
        }                                                                   \
        __builtin_amdgcn_sched_barrier(0);                                  \
    } while (0)

// Consume sub-batch SB from buffer BUF (L-values broadcast from registers).
#define PROC(BUF, SB)                                                       \
    do {                                                                    \
        _Pragma("unroll")                                                   \
        for (int j_ = 0; j_ < 8; ++j_) {                                    \
            int k_ = (SB) * 8 + j_;                                         \
            float l0r_ = rl_f(vl0r, k_);                                    \
            float l0i_ = rl_f(vl0i, k_);                                    \
            float l1r_ = rl_f(vl1r, k_);                                    \
            float l1i_ = rl_f(vl1i, k_);                                    \
            a0 += l0r_ * xr##BUF[j_] - l0i_ * xi##BUF[j_];                  \
            b0 += l0i_ * xr##BUF[j_] + l0r_ * xi##BUF[j_];                  \
            a1 += l1r_ * xr##BUF[j_] - l1i_ * xi##BUF[j_];                  \
            b1 += l1i_ * xr##BUF[j_] + l1r_ * xi##BUF[j_];                  \
        }                                                                   \
    } while (0)

template<int NSB>
__device__ __forceinline__ void proc_row(
    int vcol, float vl0r, float vl0i, float vl1r, float vl1i,
    const float* __restrict__ Xr, const float* __restrict__ Xi, int lane,
    float& a0, float& b0, float& a1, float& b1)
{
    float xrA[8], xiA[8], xrB[8], xiB[8];
    ISSUE(A, 0);
    if constexpr (NSB > 1) ISSUE(B, 1);
    PROC(A, 0);
    if constexpr (NSB > 2) ISSUE(A, 2);
    if constexpr (NSB > 1) PROC(B, 1);
    if constexpr (NSB > 3) ISSUE(B, 3);
    if constexpr (NSB > 2) PROC(A, 2);
    if constexpr (NSB > 4) ISSUE(A, 4);
    if constexpr (NSB > 3) PROC(B, 3);
    if constexpr (NSB > 5) ISSUE(B, 5);
    if constexpr (NSB > 4) PROC(A, 4);
    if constexpr (NSB > 6) ISSUE(A, 6);
    if constexpr (NSB > 5) PROC(B, 5);
    if constexpr (NSB > 7) ISSUE(B, 7);
    if constexpr (NSB > 6) PROC(A, 6);
    if constexpr (NSB > 7) PROC(B, 7);
}

// Kernel B: fused spmm (wave owns row, register accumulation, lane=channel)
// + per-row matvec with w staged in LDS. Per 64-edge batch: ONE lane-parallel
// metadata load round, then gathers ping-ponged 16-in-flight.
__global__ __launch_bounds__(BLOCK, 6) void sdconv_fused(
    const float* __restrict__ Xr, const float* __restrict__ Xi,
    const float* __restrict__ Lr, const float* __restrict__ Li,
    const float* __restrict__ W, const float* __restrict__ bias,
    const int* __restrict__ ecol, const int* __restrict__ rp,
    float* __restrict__ outR, float* __restrict__ outI,
    int N, int E)
{
    __shared__ float2 w_lds[CH * CH];                               // 32 KB {w0,w1}
    __shared__ __align__(16) float scratch[ROWS_PER_BLOCK][4 * CH]; // 8 KB

    const int t    = threadIdx.x;
    const int wave = t >> 6;
    const int lane = t & 63;
    const int row  = blockIdx.x * ROWS_PER_BLOCK + wave;

    // early independent loads
    float bv = bias[lane];
    int start = 0, end = 0;
    if (row < N) { start = rp[row]; end = rp[row + 1]; }
    start = __builtin_amdgcn_readfirstlane(start);
    end   = __builtin_amdgcn_readfirstlane(end);

    // stage packed W (no barrier yet -- only the epilogue reads it)
    for (int i = t; i < CH * CH; i += BLOCK)
        w_lds[i] = make_float2(W[i], W[CH * CH + i]);

    const float* __restrict__ Lr1 = Lr + E;
    const float* __restrict__ Li1 = Li + E;

    float a0 = 0.f, b0 = 0.f, a1 = 0.f, b1 = 0.f;

    for (int base = start; base < end; base += 64) {
        // one coalesced metadata round for up to 64 edges (lane j = edge j)
        int  eid  = base + lane;
        bool ok   = eid < end;
        int  eidc = ok ? eid : start;
        int   vcol = ecol[eidc];
        float vl0r = ok ? Lr[eidc]  : 0.f;
        float vl0i = ok ? Li[eidc]  : 0.f;
        float vl1r = ok ? Lr1[eidc] : 0.f;
        float vl1i = ok ? Li1[eidc] : 0.f;

        int m = end - base; if (m > 64) m = 64;   // wave-uniform
        int nsb = (m + 7) >> 3;                   // 1..8 sub-batches of 8
        switch (nsb) {
            case 1: proc_row<1>(vcol, vl0r, vl0i, vl1r, vl1i, Xr, Xi, lane, a0, b0, a1, b1); break;
            case 2: proc_row<2>(vcol, vl0r, vl0i, vl1r, vl1i, Xr, Xi, lane, a0, b0, a1, b1); break;
            case 3: proc_row<3>(vcol, vl0r, vl0i, vl1r, vl1i, Xr, Xi, lane, a0, b0, a1, b1); break;
            case 4: proc_row<4>(vcol, vl0r, vl0i, vl1r, vl1i, Xr, Xi, lane, a0, b0, a1, b1); break;
            case 5: proc_row<5>(vcol, vl0r, vl0i, vl1r, vl1i, Xr, Xi, lane, a0, b0, a1, b1); break;
            case 6: proc_row<6>(vcol, vl0r, vl0i, vl1r, vl1i, Xr, Xi, lane, a0, b0, a1, b1); break;
            case 7: proc_row<7>(vcol, vl0r, vl0i, vl1r, vl1i, Xr, Xi, lane, a0, b0, a1, b1); break;
            default: proc_row<8>(vcol, vl0r, vl0i, vl1r, vl1i, Xr, Xi, lane, a0, b0, a1, b1); break;
        }
    }

    // stage per-wave accumulator vectors (lane=channel -> epilogue needs all channels)
    float* sl = scratch[wave];
    sl[0 * CH + lane] = a0;
    sl[1 * CH + lane] = a1;
    sl[2 * CH + lane] = b0;
    sl[3 * CH + lane] = b1;
    __syncthreads();   // covers w_lds staging AND scratch writes

    if (row >= N) return;

    // matvec: out[j] = bias[j] + sum_c A0[c] w0[c][j] + A1[c] w1[c][j]  (j = lane)
    float accR = bv, accI = bv;
    #pragma unroll
    for (int c4 = 0; c4 < CH / 4; ++c4) {
        float4 A0 = *(const float4*)&sl[0 * CH + c4 * 4];  // b128 broadcast reads
        float4 A1 = *(const float4*)&sl[1 * CH + c4 * 4];
        float4 B0 = *(const float4*)&sl[2 * CH + c4 * 4];
        float4 B1 = *(const float4*)&sl[3 * CH + c4 * 4];
        #pragma unroll
        for (int cc = 0; cc < 4; ++cc) {
            int c = c4 * 4 + cc;
            float2 wv = w_lds[c * CH + lane];              // ds_read_b64, conflict-free
            float a0c = (&A0.x)[cc], a1c = (&A1.x)[cc];
            float b0c = (&B0.x)[cc], b1c = (&B1.x)[cc];
            accR += a0c * wv.x + a1c * wv.y;
            accI += b0c * wv.x + b1c * wv.y;
        }
    }
    outR[(size_t)row * CH + lane] = accR;
    outI[(size_t)row * CH + lane] = accI;
}

extern "C" void kernel_launch(void* const* d_in, const int* in_sizes, int n_in,
                              void* d_out, int out_size, void* d_ws, size_t ws_size,
                              hipStream_t stream)
{
    const float* Xr   = (const float*)d_in[0];
    const float* Xi   = (const float*)d_in[1];
    const float* Lr   = (const float*)d_in[2];
    const float* Li   = (const float*)d_in[3];
    const float* W    = (const float*)d_in[4];
    const float* bias = (const float*)d_in[5];
    const int*   erow = (const int*)d_in[6];
    const int*   ecol = (const int*)d_in[7];

    const int N = in_sizes[0] / CH;
    const int E = in_sizes[6];

    int* rp = (int*)d_ws;                 // (N+1) ints of scratch
    float* outR = (float*)d_out;
    float* outI = outR + (size_t)N * CH;

    int nb_rp = (N + 1 + 255) / 256;
    hipLaunchKernelGGL(build_row_ptr, dim3(nb_rp), dim3(256), 0, stream,
                       erow, rp, N, E);

    int nb = (N + ROWS_PER_BLOCK - 1) / ROWS_PER_BLOCK;
    hipLaunchKernelGGL(sdconv_fused, dim3(nb), dim3(BLOCK), 0, stream,
                       Xr, Xi, Lr, Li, W, bias, ecol, rp, outR, outI, N, E);
}

// Round 8
// 157.987 us; speedup vs baseline: 14.9841x; 1.0682x over previous
//
#include <hip/hip_runtime.h>

#define CH 64
#define RPB 8
#define BLOCK (RPB * 64)

typedef short short8 __attribute__((ext_vector_type(8)));
typedef float f32x4 __attribute__((ext_vector_type(4)));
typedef unsigned short ushort8v __attribute__((ext_vector_type(8)));

__device__ __forceinline__ unsigned short f2bf(float f) {
    unsigned u = __float_as_uint(f);
    u += 0x7fff + ((u >> 16) & 1);          // round-to-nearest-even
    return (unsigned short)(u >> 16);
}
__device__ __forceinline__ float bf2f(unsigned short h) {
    return __uint_as_float(((unsigned)h) << 16);
}
__device__ __forceinline__ float rl_f(float v, int l) {
    return __uint_as_float(__builtin_amdgcn_readlane(__float_as_uint(v), l));
}

// Kernel A: row_ptr[r] = first edge index e with edge_row[e] >= r  (r in [0, N])
__global__ __launch_bounds__(256) void build_row_ptr(
    const int* __restrict__ erow, int* __restrict__ rp, int N, int E)
{
    int r = blockIdx.x * 256 + threadIdx.x;
    if (r > N) return;
    int lo = 0, len = E;
    while (len > 0) {
        int half = len >> 1;
        int probe = lo + half;
        int v = erow[probe];
        if (v < r) { lo = probe + 1; len -= half + 1; }
        else { len = half; }
    }
    rp[r] = lo;
}

// Kernel A2: precompute W as bf16 hi/lo fragments in mfma_16x16x32 B-layout.
// B[kk][n], kk in [0,128): kk<64 -> w0[kk][n], else w1[kk-64][n].
// lane l -> col n = nt*16 + (l&15), elems kk = ks*32 + (l>>4)*8 + j.
// ws layout: wf[((h*4+ks)*4+nt)*512 + lane*8 + j]  (2*4*4*64*8 ushort = 32 KB)
__global__ __launch_bounds__(256) void prep_wfrag(
    const float* __restrict__ W, unsigned short* __restrict__ wf)
{
    int tid = blockIdx.x * 256 + threadIdx.x;
    if (tid >= 2048) return;
    int lane = tid & 63;
    int nt = (tid >> 6) & 3;
    int ks = (tid >> 8) & 3;
    int h  = (tid >> 10) & 1;
    int n  = nt * 16 + (lane & 15);
    int g  = lane >> 4;
    ushort8v o;
    #pragma unroll
    for (int j = 0; j < 8; ++j) {
        int kk = ks * 32 + g * 8 + j;
        float w = (kk < 64) ? W[kk * 64 + n] : W[4096 + (kk - 64) * 64 + n];
        unsigned short hi = f2bf(w);
        o[j] = h ? f2bf(w - bf2f(hi)) : hi;
    }
    *(ushort8v*)(wf + (size_t)tid * 8) = o;
}

// ---- round-4 spmm machinery (PROVEN correct + fast), verbatim ----
#define ISSUE(BUF, SB)                                                      \
    do {                                                                    \
        _Pragma("unroll")                                                   \
        for (int j_ = 0; j_ < 8; ++j_) {                                    \
            int c_ = __builtin_amdgcn_readlane(vcol, (SB) * 8 + j_);        \
            xr##BUF[j_] = Xr[(size_t)c_ * CH + lane];                       \
            xi##BUF[j_] = Xi[(size_t)c_ * CH + lane];                       \
        }                                                                   \
        __builtin_amdgcn_sched_barrier(0);                                  \
    } while (0)

#define PROC(BUF, SB)                                                       \
    do {                                                                    \
        _Pragma("unroll")                                                   \
        for (int j_ = 0; j_ < 8; ++j_) {                                    \
            int k_ = (SB) * 8 + j_;                                         \
            float l0r_ = rl_f(vl0r, k_);                                    \
            float l0i_ = rl_f(vl0i, k_);                                    \
            float l1r_ = rl_f(vl1r, k_);                                    \
            float l1i_ = rl_f(vl1i, k_);                                    \
            a0 += l0r_ * xr##BUF[j_] - l0i_ * xi##BUF[j_];                  \
            b0 += l0i_ * xr##BUF[j_] + l0r_ * xi##BUF[j_];                  \
            a1 += l1r_ * xr##BUF[j_] - l1i_ * xi##BUF[j_];                  \
            b1 += l1i_ * xr##BUF[j_] + l1r_ * xi##BUF[j_];                  \
        }                                                                   \
    } while (0)

template<int NSB>
__device__ __forceinline__ void proc_row(
    int vcol, float vl0r, float vl0i, float vl1r, float vl1i,
    const float* __restrict__ Xr, const float* __restrict__ Xi, int lane,
    float& a0, float& b0, float& a1, float& b1)
{
    float xrA[8], xiA[8], xrB[8], xiB[8];
    ISSUE(A, 0);
    if constexpr (NSB > 1) ISSUE(B, 1);
    PROC(A, 0);
    if constexpr (NSB > 2) ISSUE(A, 2);
    if constexpr (NSB > 1) PROC(B, 1);
    if constexpr (NSB > 3) ISSUE(B, 3);
    if constexpr (NSB > 2) PROC(A, 2);
    if constexpr (NSB > 4) ISSUE(A, 4);
    if constexpr (NSB > 3) PROC(B, 3);
    if constexpr (NSB > 5) ISSUE(B, 5);
    if constexpr (NSB > 4) PROC(A, 4);
    if constexpr (NSB > 6) ISSUE(A, 6);
    if constexpr (NSB > 5) PROC(B, 5);
    if constexpr (NSB > 7) ISSUE(B, 7);
    if constexpr (NSB > 6) PROC(A, 6);
    if constexpr (NSB > 7) PROC(B, 7);
}

// Kernel B: r4 spmm (wave owns row, lane-parallel metadata + readlane,
// 16-deep gathers) + dual-chain MFMA epilogue (waves 0-3 real, 4-7 imag;
// A rows 0-7 only, rows 8-15 zero, C rows 8-15 discarded).
__global__ __launch_bounds__(BLOCK, 6) void sdconv_fused(
    const float* __restrict__ Xr, const float* __restrict__ Xi,
    const float* __restrict__ Lr, const float* __restrict__ Li,
    const float* __restrict__ bias,
    const int* __restrict__ ecol, const int* __restrict__ rp,
    const unsigned short* __restrict__ wf,
    float* __restrict__ outR, float* __restrict__ outI,
    int N, int E)
{
    // [arr(4)][blockrow(8)][68]: 0,1 = a0,a1 (real); 2,3 = b0,b1 (imag)
    __shared__ __align__(16) float sA[4 * RPB * 68];  // 8.7 KB

    const int t    = threadIdx.x;
    const int wave = t >> 6;
    const int lane = t & 63;
    const int r0   = blockIdx.x * RPB;
    const int row  = r0 + wave;

    int start = 0, end = 0;
    if (row < N) { start = rp[row]; end = rp[row + 1]; }
    start = __builtin_amdgcn_readfirstlane(start);
    end   = __builtin_amdgcn_readfirstlane(end);

    const float* __restrict__ Lr1 = Lr + E;
    const float* __restrict__ Li1 = Li + E;

    float a0 = 0.f, b0 = 0.f, a1 = 0.f, b1 = 0.f;

    for (int base = start; base < end; base += 64) {
        // one coalesced metadata round for up to 64 edges (lane j = edge j)
        int  eid  = base + lane;
        bool ok   = eid < end;
        int  eidc = ok ? eid : start;
        int   vcol = ecol[eidc];
        float vl0r = ok ? Lr[eidc]  : 0.f;
        float vl0i = ok ? Li[eidc]  : 0.f;
        float vl1r = ok ? Lr1[eidc] : 0.f;
        float vl1i = ok ? Li1[eidc] : 0.f;

        int m = end - base; if (m > 64) m = 64;   // wave-uniform
        int nsb = (m + 7) >> 3;                   // 1..8 sub-batches of 8
        switch (nsb) {
            case 1: proc_row<1>(vcol, vl0r, vl0i, vl1r, vl1i, Xr, Xi, lane, a0, b0, a1, b1); break;
            case 2: proc_row<2>(vcol, vl0r, vl0i, vl1r, vl1i, Xr, Xi, lane, a0, b0, a1, b1); break;
            case 3: proc_row<3>(vcol, vl0r, vl0i, vl1r, vl1i, Xr, Xi, lane, a0, b0, a1, b1); break;
            case 4: proc_row<4>(vcol, vl0r, vl0i, vl1r, vl1i, Xr, Xi, lane, a0, b0, a1, b1); break;
            case 5: proc_row<5>(vcol, vl0r, vl0i, vl1r, vl1i, Xr, Xi, lane, a0, b0, a1, b1); break;
            case 6: proc_row<6>(vcol, vl0r, vl0i, vl1r, vl1i, Xr, Xi, lane, a0, b0, a1, b1); break;
            case 7: proc_row<7>(vcol, vl0r, vl0i, vl1r, vl1i, Xr, Xi, lane, a0, b0, a1, b1); break;
            default: proc_row<8>(vcol, vl0r, vl0i, vl1r, vl1i, Xr, Xi, lane, a0, b0, a1, b1); break;
        }
    }

    sA[(0 * RPB + wave) * 68 + lane] = a0;
    sA[(1 * RPB + wave) * 68 + lane] = a1;
    sA[(2 * RPB + wave) * 68 + lane] = b0;
    sA[(3 * RPB + wave) * 68 + lane] = b1;
    __syncthreads();

    // Dual-chain MFMA epilogue: C[8x64] = A[8x128] x B[128x64] per chain.
    // waves 0-3: real (arrays 0,1); waves 4-7: imag (arrays 2,3).
    // bf16 hi/lo split: AhBh + AlBh + AhBl (f32 accumulate).
    const int nt    = wave & 3;
    const int abase = (wave < 4) ? 0 : 2;
    const int cidx  = lane & 15;
    const int g     = lane >> 4;
    const int ar    = lane & 15;

    f32x4 acc = {0.f, 0.f, 0.f, 0.f};
    #pragma unroll
    for (int ks = 0; ks < 4; ++ks) {
        const int kk0 = ks * 32 + g * 8;
        short8 ah = {0, 0, 0, 0, 0, 0, 0, 0};
        short8 al = {0, 0, 0, 0, 0, 0, 0, 0};
        if (ar < 8) {   // only validated A rows carry data
            const int arr = abase + (kk0 >= 64 ? 1 : 0);
            const float* src = &sA[(arr * RPB + ar) * 68 + (kk0 & 63)];
            float4 v0 = *(const float4*)src;
            float4 v1 = *(const float4*)(src + 4);
            float av[8] = {v0.x, v0.y, v0.z, v0.w, v1.x, v1.y, v1.z, v1.w};
            #pragma unroll
            for (int j = 0; j < 8; ++j) {
                unsigned short hb = f2bf(av[j]);
                ah[j] = (short)hb;
                al[j] = (short)f2bf(av[j] - bf2f(hb));
            }
        }
        short8 bh = *(const short8*)(wf + (size_t)((0 * 4 + ks) * 4 + nt) * 512 + lane * 8);
        short8 bl = *(const short8*)(wf + (size_t)((1 * 4 + ks) * 4 + nt) * 512 + lane * 8);
        acc = __builtin_amdgcn_mfma_f32_16x16x32_bf16(ah, bh, acc, 0, 0, 0);
        acc = __builtin_amdgcn_mfma_f32_16x16x32_bf16(al, bh, acc, 0, 0, 0);
        acc = __builtin_amdgcn_mfma_f32_16x16x32_bf16(ah, bl, acc, 0, 0, 0);
    }

    // C/D: col=lane&15, row=(lane>>4)*4+q -> rows 0-7 live in lanes g<2
    if (g < 2) {
        float bv = bias[nt * 16 + cidx];
        float* dst = (wave < 4) ? outR : outI;
        #pragma unroll
        for (int q = 0; q < 4; ++q) {
            int grow = r0 + g * 4 + q;
            if (grow < N)
                dst[(size_t)grow * CH + nt * 16 + cidx] = acc[q] + bv;
        }
    }
}

extern "C" void kernel_launch(void* const* d_in, const int* in_sizes, int n_in,
                              void* d_out, int out_size, void* d_ws, size_t ws_size,
                              hipStream_t stream)
{
    const float* Xr   = (const float*)d_in[0];
    const float* Xi   = (const float*)d_in[1];
    const float* Lr   = (const float*)d_in[2];
    const float* Li   = (const float*)d_in[3];
    const float* W    = (const float*)d_in[4];
    const float* bias = (const float*)d_in[5];
    const int*   erow = (const int*)d_in[6];
    const int*   ecol = (const int*)d_in[7];

    const int N = in_sizes[0] / CH;
    const int E = in_sizes[6];

    int* rp = (int*)d_ws;
    size_t woff = (((size_t)(N + 1) * 4) + 255) & ~(size_t)255;
    unsigned short* wfrag = (unsigned short*)((char*)d_ws + woff);

    float* outR = (float*)d_out;
    float* outI = outR + (size_t)N * CH;

    hipLaunchKernelGGL(build_row_ptr, dim3((N + 1 + 255) / 256), dim3(256), 0, stream,
                       erow, rp, N, E);
    hipLaunchKernelGGL(prep_wfrag, dim3(8), dim3(256), 0, stream, W, wfrag);

    int nb = (N + RPB - 1) / RPB;
    hipLaunchKernelGGL(sdconv_fused, dim3(nb), dim3(BLOCK), 0, stream,
                       Xr, Xi, Lr, Li, bias, ecol, rp, wfrag, outR, outI, N, E);
}